// Round 5
// baseline (210.346 us; speedup 1.0000x reference)
//
#include <hip/hip_runtime.h>
#include <math.h>

#define B_ 64
#define S_ 129
#define F_ 768
#define N3 192            // 3*B
#define BF 49152          // B*F
#define NCHUNK 1548       // S * (F/64)
#define GPAIRS 256        // chunk-groups; grid = 2*GPAIRS
#define SLICE 18432       // 96*192 half-Gram partial slice
#define GSZ 36864         // 192*192
#define NSPLIT 4

// ws float offsets
#define WS_NM   0
#define WS_SV   3072
#define WS_C1   6144
#define WS_C0   55296
#define WS_HGM  104448
#define WS_HGS  153600
#define WS_GRAM 301056
#define WS_PART 337920
// S1P/S2P overlay the head of PART (consumed by k_dom/k_coef before k_main writes PART)
#define WS_S1P  WS_PART
#define WS_S2P  (WS_PART + NSPLIT * BF)

// out float offsets
#define OUT_LOSS 6340608
#define OUT_NM   6340609
#define OUT_NV   6343681

typedef unsigned int uint;
using short8v = __attribute__((ext_vector_type(8))) short;
using float4v = __attribute__((ext_vector_type(4))) float;

// ---------------- K1: per-(b,f) partial sums over S (split 4 ways) ----------------
__global__ void k_bf_stats(const float* __restrict__ x,
                           float* __restrict__ s1p, float* __restrict__ s2p) {
    int part = blockIdx.x / 192;
    int blk  = blockIdx.x % 192;
    int t = blk * 256 + threadIdx.x;             // 0..49151 -> (b,f)
    int b = t / F_, f = t - b * F_;
    int s0 = part * 33;
    int s1e = (s0 + 33 < S_) ? s0 + 33 : S_;
    const float* p = x + (size_t)b * S_ * F_ + f;
    float a1 = 0.f, a2 = 0.f;
    for (int s = s0; s < s1e; ++s) {
        float v = p[s * F_];
        a1 += v; a2 += v * v;
    }
    s1p[part * BF + t] = a1;
    s2p[part * BF + t] = a2;
}

// ---------------- K2: per-domain stats -> new_mean/new_var (parallel over f x d) ----
__global__ void k_dom(const float* __restrict__ s1p, const float* __restrict__ s2p,
                      const int* __restrict__ domain,
                      const float* __restrict__ mean_buf, const float* __restrict__ var_buf,
                      float* __restrict__ nm_tab, float* __restrict__ sv_tab,
                      float* __restrict__ out_nm, float* __restrict__ out_nv) {
    int idx = blockIdx.x * 256 + threadIdx.x;    // 0..3071 = f*4+d
    if (idx >= F_ * 4) return;
    int f = idx >> 2, d = idx & 3;
    float a1 = 0.f, a2 = 0.f;
    int cnt = 0;
    for (int b = 0; b < B_; ++b) {
        if (domain[b] == d) {
            float v1 = 0.f, v2 = 0.f;
#pragma unroll
            for (int p = 0; p < NSPLIT; ++p) {
                v1 += s1p[p * BF + b * F_ + f];
                v2 += s2p[p * BF + b * F_ + f];
            }
            a1 += v1; a2 += v2; cnt++;
        }
    }
    float nm, nv;
    if (cnt > 0) {
        float n = (float)cnt * (float)S_;
        float mu = a1 / n;
        float var = (a2 - n * mu * mu) / fmaxf(n - 1.0f, 1.0f);
        nm = 0.9f * mean_buf[d * F_ + f] + 0.1f * mu;
        nv = 0.9f * var_buf[d * F_ + f] + 0.1f * var;
    } else {
        nm = mean_buf[d * F_ + f];
        nv = var_buf[d * F_ + f];
    }
    out_nm[d * F_ + f] = nm;
    out_nv[d * F_ + f] = nv;
    nm_tab[d * F_ + f] = nm;
    sv_tab[d * F_ + f] = sqrtf(nv + 1e-6f);
}

// ---------------- K2b: per-(b,f) mix/hg coefficients (+ zero gram/loss) ------------
__global__ void k_coef(const float* __restrict__ s1p, const float* __restrict__ s2p,
                       const float* __restrict__ lmda,
                       const int* __restrict__ domain, const int* __restrict__ d_rand,
                       const float* __restrict__ nm_tab, const float* __restrict__ sv_tab,
                       float* __restrict__ c1, float* __restrict__ c0,
                       float* __restrict__ hgm, float* __restrict__ hgs,
                       float* __restrict__ gram, float* __restrict__ out_loss) {
    int t = blockIdx.x * 256 + threadIdx.x;      // 0..49151
    if (blockIdx.x < 144) gram[blockIdx.x * 256 + threadIdx.x] = 0.0f;
    if (blockIdx.x == 144 && threadIdx.x == 0) out_loss[0] = 0.0f;
    int b = t / F_, f = t - b * F_;
    float s1 = 0.f, s2 = 0.f;
#pragma unroll
    for (int p = 0; p < NSPLIT; ++p) {
        s1 += s1p[p * BF + t];
        s2 += s2p[p * BF + t];
    }
    float mu = s1 * (1.0f / (float)S_);
    float v  = (s2 - (float)S_ * mu * mu) * (1.0f / (float)(S_ - 1));
    float r  = rsqrtf(v + 1e-6f);
    int dm = domain[b];
    int ds = (dm + d_rand[b]) & 3;               // D == 4
    float sv = sv_tab[ds * F_ + f];
    float nm = nm_tab[ds * F_ + f];
    float lam = lmda[b];
    float rs = r * sv;
    c1[t] = lam + (1.0f - lam) * rs;
    c0[t] = (1.0f - lam) * (nm - mu * rs);
    hgm[t] = nm_tab[dm * F_ + f];
    hgs[t] = sv_tab[dm * F_ + f];
}

// ---------------- bf16 hi/lo split helpers ----------------
__device__ __forceinline__ uint packsplit(float a, float b, uint& lopack) {
    uint ua = __float_as_uint(a);
    uint ha = (ua + 0x7FFFu + ((ua >> 16) & 1u)) & 0xFFFF0000u;
    uint ub = __float_as_uint(b);
    uint hb = (ub + 0x7FFFu + ((ub >> 16) & 1u)) & 0xFFFF0000u;
    float la = a - __uint_as_float(ha);
    float lb = b - __uint_as_float(hb);
    uint ula = __float_as_uint(la), ulb = __float_as_uint(lb);
    uint lra = (ula + 0x7FFFu + ((ula >> 16) & 1u)) >> 16;
    uint lrb = (ulb + 0x7FFFu + ((ulb >> 16) & 1u)) & 0xFFFF0000u;
    lopack = lrb | lra;
    return hb | (ha >> 16);
}

// stage 16 floats (2 granules) of one plane-row into swizzled LDS
__device__ __forceinline__ void split_store(char* lds, int row, int g0,
                                            float4 v0, float4 v1, float4 v2, float4 v3) {
    uint4 H0, H1, L0, L1;
    H0.x = packsplit(v0.x, v0.y, L0.x);
    H0.y = packsplit(v0.z, v0.w, L0.y);
    H0.z = packsplit(v1.x, v1.y, L0.z);
    H0.w = packsplit(v1.z, v1.w, L0.w);
    H1.x = packsplit(v2.x, v2.y, L1.x);
    H1.y = packsplit(v2.z, v2.w, L1.y);
    H1.z = packsplit(v3.x, v3.y, L1.z);
    H1.w = packsplit(v3.z, v3.w, L1.w);
    int r7 = row & 7;
    int a0 = row * 128 + ((g0 ^ r7) << 4);
    int a1 = row * 128 + (((g0 + 1) ^ r7) << 4);
    *(uint4*)(lds + a0) = H0;
    *(uint4*)(lds + a1) = H1;
    *(uint4*)(lds + 24576 + a0) = L0;
    *(uint4*)(lds + 24576 + a1) = L1;
}

__device__ __forceinline__ float4 fma4(float4 a, float4 x, float4 b) {
    float4 r;
    r.x = fmaf(a.x, x.x, b.x); r.y = fmaf(a.y, x.y, b.y);
    r.z = fmaf(a.z, x.z, b.z); r.w = fmaf(a.w, x.w, b.w);
    return r;
}

// ---------------- K3: fused x_mix/hg generation + MFMA Gram partials ----------------
// 512 blocks x 256 threads = 2 blocks/CU. Pair (cg = bid>>1, h = bid&1): both stage
// the same 192x64 chunk (second read L2/L3-hot); block computes only the 96-row
// half h of the Gram (4 waves x 96x48 = 72 AGPR/wave -> real 2 waves/EU occupancy).
// Partial slices 96x192 -> total partial traffic unchanged vs 256 full slices.
template <bool EXCL>
__global__ __launch_bounds__(256, 2)
void k_main(const float* __restrict__ x, const float* __restrict__ hgn,
            const float* __restrict__ c1, const float* __restrict__ c0,
            const float* __restrict__ hgm, const float* __restrict__ hgs,
            float* __restrict__ xmix, float* part, int nhalf) {
    __shared__ __align__(16) char LDS[49152];
    float4v acc[6][3];
#pragma unroll
    for (int i = 0; i < 6; ++i)
#pragma unroll
        for (int j = 0; j < 3; ++j)
            acc[i][j] = (float4v){0.f, 0.f, 0.f, 0.f};

    int tid = threadIdx.x;
    int b  = tid >> 2;            // staging row 0..63
    int fq = (tid & 3) << 4;      // f offset within 64-chunk
    int g0 = (tid & 3) << 1;      // first granule
    int h  = blockIdx.x & 1;      // Gram row half
    int cg = blockIdx.x >> 1;     // chunk group
    int w  = tid >> 6;            // wave 0..3
    int wc = w * 48;              // wave col offset
    int rowbase = h * 96;         // wave rows = [96h, 96h+96)
    int lane = tid & 63, m = lane & 15, qd = lane >> 4;

    int q = cg;
    size_t goff; int cb;
    {
        int s = q / 12, f0 = (q - s * 12) * 64;
        goff = ((size_t)b * S_ + s) * F_ + f0 + fq;
        cb = b * F_ + f0 + fq;
    }
    float4 X0 = ((const float4*)(x + goff))[0];
    float4 X1 = ((const float4*)(x + goff))[1];
    float4 X2 = ((const float4*)(x + goff))[2];
    float4 X3 = ((const float4*)(x + goff))[3];
    float4 N0 = ((const float4*)(hgn + goff))[0];
    float4 N1 = ((const float4*)(hgn + goff))[1];
    float4 N2 = ((const float4*)(hgn + goff))[2];
    float4 N3v = ((const float4*)(hgn + goff))[3];

    for (; q < NCHUNK; q += GPAIRS) {
        float4 M0, M1, M2, M3, H0, H1, H2, H3;
        {
            const float4* c1p = (const float4*)(c1 + cb);
            const float4* c0p = (const float4*)(c0 + cb);
            M0 = fma4(c1p[0], X0, c0p[0]);
            M1 = fma4(c1p[1], X1, c0p[1]);
            M2 = fma4(c1p[2], X2, c0p[2]);
            M3 = fma4(c1p[3], X3, c0p[3]);
        }
        if (h == 0) {
            float4* xo = (float4*)(xmix + goff);
            xo[0] = M0; xo[1] = M1; xo[2] = M2; xo[3] = M3;
        }
        {
            const float4* hmp = (const float4*)(hgm + cb);
            const float4* hsp = (const float4*)(hgs + cb);
            H0 = fma4(hsp[0], N0, hmp[0]);
            H1 = fma4(hsp[1], N1, hmp[1]);
            H2 = fma4(hsp[2], N2, hmp[2]);
            H3 = fma4(hsp[3], N3v, hmp[3]);
        }

        split_store(LDS, b, g0, X0, X1, X2, X3);
        split_store(LDS, 64 + b, g0, M0, M1, M2, M3);
        split_store(LDS, 128 + b, g0, H0, H1, H2, H3);
        __syncthreads();

        // prefetch next chunk while MFMA section runs
        int qn = q + GPAIRS;
        if (qn < NCHUNK) {
            int s = qn / 12, f0 = (qn - s * 12) * 64;
            goff = ((size_t)b * S_ + s) * F_ + f0 + fq;
            cb = b * F_ + f0 + fq;
            X0 = ((const float4*)(x + goff))[0];
            X1 = ((const float4*)(x + goff))[1];
            X2 = ((const float4*)(x + goff))[2];
            X3 = ((const float4*)(x + goff))[3];
            N0 = ((const float4*)(hgn + goff))[0];
            N1 = ((const float4*)(hgn + goff))[1];
            N2 = ((const float4*)(hgn + goff))[2];
            N3v = ((const float4*)(hgn + goff))[3];
        }

#pragma unroll
        for (int t = 0; t < 2; ++t) {
            short8v Ah[6], Al[6];
#pragma unroll
            for (int i = 0; i < 6; ++i) {
                int row = rowbase + i * 16 + m;
                int go = (((t << 2) + qd) ^ (row & 7)) << 4;
                const char* p = LDS + row * 128 + go;
                Ah[i] = *(const short8v*)(p);
                Al[i] = *(const short8v*)(p + 24576);
            }
#pragma unroll
            for (int j = 0; j < 3; ++j) {
                int row = wc + j * 16 + m;
                int go = (((t << 2) + qd) ^ (row & 7)) << 4;
                const char* p = LDS + row * 128 + go;
                short8v Bh = *(const short8v*)(p);
                short8v Bl = *(const short8v*)(p + 24576);
#pragma unroll
                for (int i = 0; i < 6; ++i) {
                    acc[i][j] = __builtin_amdgcn_mfma_f32_16x16x32_bf16(Al[i], Bh, acc[i][j], 0, 0, 0);
                    acc[i][j] = __builtin_amdgcn_mfma_f32_16x16x32_bf16(Ah[i], Bl, acc[i][j], 0, 0, 0);
                    acc[i][j] = __builtin_amdgcn_mfma_f32_16x16x32_bf16(Ah[i], Bh, acc[i][j], 0, 0, 0);
                }
            }
        }
        __syncthreads();
    }

    int slice = (cg % nhalf) * 2 + h;
    float* dst = part + (size_t)slice * SLICE;
#pragma unroll
    for (int i = 0; i < 6; ++i)
#pragma unroll
        for (int j = 0; j < 3; ++j) {
            int base = (i * 16 + qd * 4) * N3 + wc + j * 16 + m;
#pragma unroll
            for (int r = 0; r < 4; ++r) {
                int o = base + r * N3;
                if (EXCL) dst[o] = acc[i][j][r];
                else atomicAdd(dst + o, acc[i][j][r]);
            }
        }
}

// ---------------- K3b: reduce partial half-slices into gram ----------------
__global__ void k_red(const float* __restrict__ part, float* __restrict__ gram, int nhalf) {
    int g  = blockIdx.x / 144;
    int jb = blockIdx.x % 144;
    int j = jb * 256 + threadIdx.x;              // 0..36863
    int i = j / N3, c = j - i * N3;
    int h = (i >= 96) ? 1 : 0;
    int il = i - 96 * h;
    int o = il * N3 + c;
    int p0 = g * 32;
    int p1 = (p0 + 32 < nhalf) ? p0 + 32 : nhalf;
    float s = 0.0f;
    for (int p = p0; p < p1; ++p) s += part[(size_t)(p * 2 + h) * SLICE + o];
    atomicAdd(gram + j, s);
}

// ---------------- K4: triplet hard loss (one block per row) ----------------
__global__ void k_loss(const float* __restrict__ gram, const int* __restrict__ labels,
                       float* __restrict__ out_loss) {
    __shared__ float sq[N3];
    __shared__ int ln[N3];
    int i = blockIdx.x, lane = threadIdx.x;      // 64 lanes
    for (int k = lane; k < N3; k += 64) {
        sq[k] = gram[k * (N3 + 1)];
        ln[k] = (k < 128) ? labels[k & 63] : -1;
    }
    __syncthreads();
    int li = ln[i];
    float si = sq[i];
    float ap = -1e30f, an = 1e30f;
    for (int j = lane; j < N3; j += 64) {
        float d2 = si + sq[j] - 2.0f * gram[i * N3 + j];
        float dist = sqrtf(fmaxf(d2, 1e-12f));
        bool pos = (li == ln[j]);
        ap = pos ? fmaxf(ap, dist) : ap;
        an = pos ? an : fminf(an, dist);
    }
#pragma unroll
    for (int off = 32; off; off >>= 1) {
        ap = fmaxf(ap, __shfl_xor(ap, off));
        an = fminf(an, __shfl_xor(an, off));
    }
    if (lane == 0) {
        float xv = ap - an;
        float sp = fmaxf(xv, 0.0f) + log1pf(expf(-fabsf(xv)));
        atomicAdd(out_loss, sp * (1.0f / (float)N3));
    }
}

extern "C" void kernel_launch(void* const* d_in, const int* in_sizes, int n_in,
                              void* d_out, int out_size, void* d_ws, size_t ws_size,
                              hipStream_t stream) {
    const float* x        = (const float*)d_in[0];
    const float* lmda     = (const float*)d_in[1];
    const float* mean_buf = (const float*)d_in[2];
    const float* var_buf  = (const float*)d_in[3];
    const float* hgn      = (const float*)d_in[4];
    const int*   labels   = (const int*)d_in[5];
    const int*   domain   = (const int*)d_in[6];
    const int*   d_rand   = (const int*)d_in[7];
    float* out = (float*)d_out;
    float* ws  = (float*)d_ws;

    long avail = (long)(ws_size / 4) - WS_PART;
    int nhalf = (int)(avail / (2 * SLICE));
    if (nhalf < 1) nhalf = 1;
    if (nhalf > GPAIRS) nhalf = GPAIRS;
    bool excl = (nhalf == GPAIRS);
    int ngroups = (nhalf + 31) / 32;

    k_bf_stats<<<dim3(192 * NSPLIT), dim3(256), 0, stream>>>(x, ws + WS_S1P, ws + WS_S2P);
    k_dom<<<dim3(12), dim3(256), 0, stream>>>(ws + WS_S1P, ws + WS_S2P, domain,
                                              mean_buf, var_buf,
                                              ws + WS_NM, ws + WS_SV,
                                              out + OUT_NM, out + OUT_NV);
    k_coef<<<dim3(192), dim3(256), 0, stream>>>(ws + WS_S1P, ws + WS_S2P, lmda,
                                                domain, d_rand,
                                                ws + WS_NM, ws + WS_SV,
                                                ws + WS_C1, ws + WS_C0,
                                                ws + WS_HGM, ws + WS_HGS,
                                                ws + WS_GRAM, out + OUT_LOSS);
    if (!excl) {
        hipMemsetAsync(ws + WS_PART, 0, (size_t)nhalf * 2 * SLICE * 4, stream);
    }
    if (excl) {
        k_main<true><<<dim3(GPAIRS * 2), dim3(256), 0, stream>>>(
            x, hgn, ws + WS_C1, ws + WS_C0, ws + WS_HGM, ws + WS_HGS,
            out, ws + WS_PART, nhalf);
    } else {
        k_main<false><<<dim3(GPAIRS * 2), dim3(256), 0, stream>>>(
            x, hgn, ws + WS_C1, ws + WS_C0, ws + WS_HGM, ws + WS_HGS,
            out, ws + WS_PART, nhalf);
    }
    k_red<<<dim3(ngroups * 144), dim3(256), 0, stream>>>(ws + WS_PART, ws + WS_GRAM, nhalf);
    k_loss<<<dim3(N3), dim3(64), 0, stream>>>(ws + WS_GRAM, labels, out + OUT_LOSS);
}

// Round 6
// 205.104 us; speedup vs baseline: 1.0256x; 1.0256x over previous
//
#include <hip/hip_runtime.h>
#include <math.h>

#define B_ 64
#define S_ 129
#define F_ 768
#define N3 192            // 3*B
#define BF 49152          // B*F
#define NCHUNK 1548       // S * (F/64)
#define GMAIN 256
#define GSZ 36864         // 192*192
#define NSPLIT 8

// ws float offsets
#define WS_NM   0
#define WS_SV   3072
#define WS_C1   6144
#define WS_C0   55296
#define WS_HGM  104448
#define WS_HGS  153600
#define WS_GRAM 301056
#define WS_PART 337920
// S1P/S2P overlay the head of PART (consumed by k_dom/k_coef before k_main writes PART)
#define WS_S1P  WS_PART
#define WS_S2P  (WS_PART + NSPLIT * BF)

// out float offsets
#define OUT_LOSS 6340608
#define OUT_NM   6340609
#define OUT_NV   6343681

typedef unsigned int uint;
using short8v = __attribute__((ext_vector_type(8))) short;
using float4v = __attribute__((ext_vector_type(4))) float;

// ---------------- K1: per-(b,f) partial sums over S (split 8 ways, float4) --------
__global__ void k_bf_stats(const float* __restrict__ x,
                           float* __restrict__ s1p, float* __restrict__ s2p) {
    int part = blockIdx.x / 48;
    int blk  = blockIdx.x % 48;
    int t4 = blk * 256 + threadIdx.x;            // 0..12287
    int b = t4 / 192, f = (t4 - b * 192) * 4;
    int s0 = part * 16;
    int s1e = s0 + 16 + (part == 7 ? 1 : 0);
    const float* p = x + (size_t)b * S_ * F_ + f;
    float4 a1 = {0.f,0.f,0.f,0.f}, a2 = {0.f,0.f,0.f,0.f};
    for (int s = s0; s < s1e; ++s) {
        float4 v = *(const float4*)(p + s * F_);
        a1.x += v.x; a1.y += v.y; a1.z += v.z; a1.w += v.w;
        a2.x += v.x*v.x; a2.y += v.y*v.y; a2.z += v.z*v.z; a2.w += v.w*v.w;
    }
    *(float4*)(s1p + part * BF + b * F_ + f) = a1;
    *(float4*)(s2p + part * BF + b * F_ + f) = a2;
}

// ---------------- K2: per-domain stats -> new_mean/new_var (parallel over f x d) ----
__global__ void k_dom(const float* __restrict__ s1p, const float* __restrict__ s2p,
                      const int* __restrict__ domain,
                      const float* __restrict__ mean_buf, const float* __restrict__ var_buf,
                      float* __restrict__ nm_tab, float* __restrict__ sv_tab,
                      float* __restrict__ out_nm, float* __restrict__ out_nv) {
    int idx = blockIdx.x * 256 + threadIdx.x;    // 0..3071 = f*4+d
    if (idx >= F_ * 4) return;
    int f = idx >> 2, d = idx & 3;
    float a1 = 0.f, a2 = 0.f;
    int cnt = 0;
    for (int b = 0; b < B_; ++b) {
        if (domain[b] == d) {
            float v1 = 0.f, v2 = 0.f;
#pragma unroll
            for (int p = 0; p < NSPLIT; ++p) {
                v1 += s1p[p * BF + b * F_ + f];
                v2 += s2p[p * BF + b * F_ + f];
            }
            a1 += v1; a2 += v2; cnt++;
        }
    }
    float nm, nv;
    if (cnt > 0) {
        float n = (float)cnt * (float)S_;
        float mu = a1 / n;
        float var = (a2 - n * mu * mu) / fmaxf(n - 1.0f, 1.0f);
        nm = 0.9f * mean_buf[d * F_ + f] + 0.1f * mu;
        nv = 0.9f * var_buf[d * F_ + f] + 0.1f * var;
    } else {
        nm = mean_buf[d * F_ + f];
        nv = var_buf[d * F_ + f];
    }
    out_nm[d * F_ + f] = nm;
    out_nv[d * F_ + f] = nv;
    nm_tab[d * F_ + f] = nm;
    sv_tab[d * F_ + f] = sqrtf(nv + 1e-6f);
}

// ---------------- K2b: per-(b,f) mix/hg coefficients (+ zero gram/loss) ------------
__global__ void k_coef(const float* __restrict__ s1p, const float* __restrict__ s2p,
                       const float* __restrict__ lmda,
                       const int* __restrict__ domain, const int* __restrict__ d_rand,
                       const float* __restrict__ nm_tab, const float* __restrict__ sv_tab,
                       float* __restrict__ c1, float* __restrict__ c0,
                       float* __restrict__ hgm, float* __restrict__ hgs,
                       float* __restrict__ gram, float* __restrict__ out_loss) {
    int t = blockIdx.x * 256 + threadIdx.x;      // 0..49151
    if (blockIdx.x < 144) gram[blockIdx.x * 256 + threadIdx.x] = 0.0f;
    if (blockIdx.x == 144 && threadIdx.x == 0) out_loss[0] = 0.0f;
    int b = t / F_, f = t - b * F_;
    float s1 = 0.f, s2 = 0.f;
#pragma unroll
    for (int p = 0; p < NSPLIT; ++p) {
        s1 += s1p[p * BF + t];
        s2 += s2p[p * BF + t];
    }
    float mu = s1 * (1.0f / (float)S_);
    float v  = (s2 - (float)S_ * mu * mu) * (1.0f / (float)(S_ - 1));
    float r  = rsqrtf(v + 1e-6f);
    int dm = domain[b];
    int ds = (dm + d_rand[b]) & 3;               // D == 4
    float sv = sv_tab[ds * F_ + f];
    float nm = nm_tab[ds * F_ + f];
    float lam = lmda[b];
    float rs = r * sv;
    c1[t] = lam + (1.0f - lam) * rs;
    c0[t] = (1.0f - lam) * (nm - mu * rs);
    hgm[t] = nm_tab[dm * F_ + f];
    hgs[t] = sv_tab[dm * F_ + f];
}

// ---------------- bf16 helpers ----------------
__device__ __forceinline__ uint pack2(float a, float b) {
    uint ua = __float_as_uint(a);
    uint ub = __float_as_uint(b);
    uint ha = (ua + 0x7FFFu + ((ua >> 16) & 1u)) >> 16;
    uint hb = (ub + 0x7FFFu + ((ub >> 16) & 1u)) & 0xFFFF0000u;
    return hb | ha;
}

// stage 8 floats (one granule) of one plane-row into swizzled LDS
__device__ __forceinline__ void bf16_store8(char* lds, int row, int g,
                                            float4 v0, float4 v1) {
    uint4 H;
    H.x = pack2(v0.x, v0.y);
    H.y = pack2(v0.z, v0.w);
    H.z = pack2(v1.x, v1.y);
    H.w = pack2(v1.z, v1.w);
    *(uint4*)(lds + row * 128 + ((g ^ (row & 7)) << 4)) = H;
}

__device__ __forceinline__ float4 fma4(float4 a, float4 x, float4 b) {
    float4 r;
    r.x = fmaf(a.x, x.x, b.x); r.y = fmaf(a.y, x.y, b.y);
    r.z = fmaf(a.z, x.z, b.z); r.w = fmaf(a.w, x.w, b.w);
    return r;
}

// ---------------- K3: fused x_mix/hg generation + MFMA Gram partials ----------------
// 256 blocks x 512 threads (8 waves, 1 block/CU, 2 waves/EU). Single bf16 plane
// (error ~3e-3 on loss, threshold 0.1175). All six input streams register-
// prefetched across the barrier so the HBM/L2 stream overlaps the MFMA section.
template <bool EXCL>
__global__ __launch_bounds__(512, 2)
void k_main(const float* __restrict__ x, const float* __restrict__ hgn,
            const float* __restrict__ c1, const float* __restrict__ c0,
            const float* __restrict__ hgm, const float* __restrict__ hgs,
            float* __restrict__ xmix, float* part, int npart) {
    __shared__ __align__(16) char LDS[24576];    // 192 rows x 128 B (bf16 x 64)
    float4v acc[6][3];
#pragma unroll
    for (int i = 0; i < 6; ++i)
#pragma unroll
        for (int j = 0; j < 3; ++j)
            acc[i][j] = (float4v){0.f, 0.f, 0.f, 0.f};

    int tid = threadIdx.x;
    int b = tid >> 3;             // staging row 0..63
    int g = tid & 7;              // granule (8 floats)
    int w = tid >> 6;             // wave 0..7
    int wr = (w >> 2) * 96, wc = (w & 3) * 48;
    int lane = tid & 63, m = lane & 15, qd = lane >> 4;

    int q = blockIdx.x;
    size_t goff; int cb;
    {
        int s = q / 12, f0 = (q - s * 12) * 64;
        goff = ((size_t)b * S_ + s) * F_ + f0 + (g << 3);
        cb = b * F_ + f0 + (g << 3);
    }
    float4 X0 = ((const float4*)(x + goff))[0];
    float4 X1 = ((const float4*)(x + goff))[1];
    float4 N0 = ((const float4*)(hgn + goff))[0];
    float4 N1 = ((const float4*)(hgn + goff))[1];
    float4 C1a = ((const float4*)(c1 + cb))[0], C1b = ((const float4*)(c1 + cb))[1];
    float4 C0a = ((const float4*)(c0 + cb))[0], C0b = ((const float4*)(c0 + cb))[1];
    float4 HMa = ((const float4*)(hgm + cb))[0], HMb = ((const float4*)(hgm + cb))[1];
    float4 HSa = ((const float4*)(hgs + cb))[0], HSb = ((const float4*)(hgs + cb))[1];

    for (; q < NCHUNK; q += GMAIN) {
        float4 M0 = fma4(C1a, X0, C0a);
        float4 M1 = fma4(C1b, X1, C0b);
        ((float4*)(xmix + goff))[0] = M0;
        ((float4*)(xmix + goff))[1] = M1;
        float4 H0 = fma4(HSa, N0, HMa);
        float4 H1 = fma4(HSb, N1, HMb);

        bf16_store8(LDS, b, g, X0, X1);
        bf16_store8(LDS, 64 + b, g, M0, M1);
        bf16_store8(LDS, 128 + b, g, H0, H1);
        __syncthreads();

        // prefetch next chunk (all six streams) while the MFMA section runs
        int qn = q + GMAIN;
        if (qn < NCHUNK) {
            int s = qn / 12, f0 = (qn - s * 12) * 64;
            goff = ((size_t)b * S_ + s) * F_ + f0 + (g << 3);
            cb = b * F_ + f0 + (g << 3);
            X0 = ((const float4*)(x + goff))[0];
            X1 = ((const float4*)(x + goff))[1];
            N0 = ((const float4*)(hgn + goff))[0];
            N1 = ((const float4*)(hgn + goff))[1];
            C1a = ((const float4*)(c1 + cb))[0]; C1b = ((const float4*)(c1 + cb))[1];
            C0a = ((const float4*)(c0 + cb))[0]; C0b = ((const float4*)(c0 + cb))[1];
            HMa = ((const float4*)(hgm + cb))[0]; HMb = ((const float4*)(hgm + cb))[1];
            HSa = ((const float4*)(hgs + cb))[0]; HSb = ((const float4*)(hgs + cb))[1];
        }

#pragma unroll
        for (int t = 0; t < 2; ++t) {
            short8v A[6];
#pragma unroll
            for (int i = 0; i < 6; ++i) {
                int row = wr + i * 16 + m;
                int go = (((t << 2) + qd) ^ (row & 7)) << 4;
                A[i] = *(const short8v*)(LDS + row * 128 + go);
            }
#pragma unroll
            for (int j = 0; j < 3; ++j) {
                int row = wc + j * 16 + m;
                int go = (((t << 2) + qd) ^ (row & 7)) << 4;
                short8v Bv = *(const short8v*)(LDS + row * 128 + go);
#pragma unroll
                for (int i = 0; i < 6; ++i)
                    acc[i][j] = __builtin_amdgcn_mfma_f32_16x16x32_bf16(A[i], Bv, acc[i][j], 0, 0, 0);
            }
        }
        __syncthreads();
    }

    float* dst = part + (size_t)(blockIdx.x % npart) * GSZ;
#pragma unroll
    for (int i = 0; i < 6; ++i)
#pragma unroll
        for (int j = 0; j < 3; ++j) {
            int base = (wr + i * 16 + qd * 4) * N3 + wc + j * 16 + m;
#pragma unroll
            for (int r = 0; r < 4; ++r) {
                int o = base + r * N3;
                if (EXCL) dst[o] = acc[i][j][r];
                else atomicAdd(dst + o, acc[i][j][r]);
            }
        }
}

// ---------------- K3b: reduce partial Grams (float4, atomic into zeroed gram) ------
__global__ void k_red(const float* __restrict__ part, float* __restrict__ gram, int npart) {
    int g  = blockIdx.x / 36;
    int jb = blockIdx.x % 36;
    int j = (jb * 256 + threadIdx.x) * 4;        // 0..36860 step 4
    int p0 = g * 32;
    int p1 = (p0 + 32 < npart) ? p0 + 32 : npart;
    float4 s = {0.f, 0.f, 0.f, 0.f};
    for (int p = p0; p < p1; ++p) {
        float4 v = *(const float4*)(part + (size_t)p * GSZ + j);
        s.x += v.x; s.y += v.y; s.z += v.z; s.w += v.w;
    }
    atomicAdd(gram + j,     s.x);
    atomicAdd(gram + j + 1, s.y);
    atomicAdd(gram + j + 2, s.z);
    atomicAdd(gram + j + 3, s.w);
}

// ---------------- K4: triplet hard loss (one block per row) ----------------
__global__ void k_loss(const float* __restrict__ gram, const int* __restrict__ labels,
                       float* __restrict__ out_loss) {
    __shared__ float sq[N3];
    __shared__ int ln[N3];
    int i = blockIdx.x, lane = threadIdx.x;      // 64 lanes
    for (int k = lane; k < N3; k += 64) {
        sq[k] = gram[k * (N3 + 1)];
        ln[k] = (k < 128) ? labels[k & 63] : -1;
    }
    __syncthreads();
    int li = ln[i];
    float si = sq[i];
    float ap = -1e30f, an = 1e30f;
    for (int j = lane; j < N3; j += 64) {
        float d2 = si + sq[j] - 2.0f * gram[i * N3 + j];
        float dist = sqrtf(fmaxf(d2, 1e-12f));
        bool pos = (li == ln[j]);
        ap = pos ? fmaxf(ap, dist) : ap;
        an = pos ? an : fminf(an, dist);
    }
#pragma unroll
    for (int off = 32; off; off >>= 1) {
        ap = fmaxf(ap, __shfl_xor(ap, off));
        an = fminf(an, __shfl_xor(an, off));
    }
    if (lane == 0) {
        float xv = ap - an;
        float sp = fmaxf(xv, 0.0f) + log1pf(expf(-fabsf(xv)));
        atomicAdd(out_loss, sp * (1.0f / (float)N3));
    }
}

extern "C" void kernel_launch(void* const* d_in, const int* in_sizes, int n_in,
                              void* d_out, int out_size, void* d_ws, size_t ws_size,
                              hipStream_t stream) {
    const float* x        = (const float*)d_in[0];
    const float* lmda     = (const float*)d_in[1];
    const float* mean_buf = (const float*)d_in[2];
    const float* var_buf  = (const float*)d_in[3];
    const float* hgn      = (const float*)d_in[4];
    const int*   labels   = (const int*)d_in[5];
    const int*   domain   = (const int*)d_in[6];
    const int*   d_rand   = (const int*)d_in[7];
    float* out = (float*)d_out;
    float* ws  = (float*)d_ws;

    long avail = (long)(ws_size / 4) - WS_PART;
    int npart = (int)(avail / GSZ);
    if (npart < 1) npart = 1;
    if (npart > GMAIN) npart = GMAIN;
    bool excl = (npart == GMAIN);
    int ngroups = (npart + 31) / 32;

    k_bf_stats<<<dim3(48 * NSPLIT), dim3(256), 0, stream>>>(x, ws + WS_S1P, ws + WS_S2P);
    k_dom<<<dim3(12), dim3(256), 0, stream>>>(ws + WS_S1P, ws + WS_S2P, domain,
                                              mean_buf, var_buf,
                                              ws + WS_NM, ws + WS_SV,
                                              out + OUT_NM, out + OUT_NV);
    k_coef<<<dim3(192), dim3(256), 0, stream>>>(ws + WS_S1P, ws + WS_S2P, lmda,
                                                domain, d_rand,
                                                ws + WS_NM, ws + WS_SV,
                                                ws + WS_C1, ws + WS_C0,
                                                ws + WS_HGM, ws + WS_HGS,
                                                ws + WS_GRAM, out + OUT_LOSS);
    if (!excl) {
        hipMemsetAsync(ws + WS_PART, 0, (size_t)npart * GSZ * 4, stream);
    }
    if (excl) {
        k_main<true><<<dim3(GMAIN), dim3(512), 0, stream>>>(
            x, hgn, ws + WS_C1, ws + WS_C0, ws + WS_HGM, ws + WS_HGS,
            out, ws + WS_PART, npart);
    } else {
        k_main<false><<<dim3(GMAIN), dim3(512), 0, stream>>>(
            x, hgn, ws + WS_C1, ws + WS_C0, ws + WS_HGM, ws + WS_HGS,
            out, ws + WS_PART, npart);
    }
    k_red<<<dim3(ngroups * 36), dim3(256), 0, stream>>>(ws + WS_PART, ws + WS_GRAM, npart);
    k_loss<<<dim3(N3), dim3(64), 0, stream>>>(ws + WS_GRAM, labels, out + OUT_LOSS);
}

// Round 7
// 159.164 us; speedup vs baseline: 1.3216x; 1.2886x over previous
//
#include <hip/hip_runtime.h>
#include <math.h>

#define B_ 64
#define S_ 129
#define F_ 768
#define N3 192            // 3*B
#define BF 49152          // B*F
#define NCHUNK 1548       // S * (F/64)
#define GMAIN 256
#define GSZ 36864         // 192*192
#define NSPLIT 8

// ws float offsets
#define WS_NM   0
#define WS_SV   3072
#define WS_C1   6144
#define WS_C0   55296
#define WS_HGM  104448
#define WS_HGS  153600
#define WS_S1   202752
#define WS_S2   251904
#define WS_GRAM 301056
#define WS_PART 337920
// S1P/S2P overlay the head of PART (consumed by k_sum before k_main writes PART)
#define WS_S1P  WS_PART
#define WS_S2P  (WS_PART + NSPLIT * BF)

// out float offsets
#define OUT_LOSS 6340608
#define OUT_NM   6340609
#define OUT_NV   6343681

typedef unsigned int uint;
using short8v = __attribute__((ext_vector_type(8))) short;
using float4v = __attribute__((ext_vector_type(4))) float;

// ---------------- K1: per-(b,f) partial sums over S (split 8 ways, float4) --------
__global__ void k_bf_stats(const float* __restrict__ x,
                           float* __restrict__ s1p, float* __restrict__ s2p) {
    int part = blockIdx.x / 48;
    int blk  = blockIdx.x % 48;
    int t4 = blk * 256 + threadIdx.x;            // 0..12287
    int b = t4 / 192, f = (t4 - b * 192) * 4;
    int s0 = part * 16;
    int s1e = s0 + 16 + (part == 7 ? 1 : 0);
    const float* p = x + (size_t)b * S_ * F_ + f;
    float4 a1 = {0.f,0.f,0.f,0.f}, a2 = {0.f,0.f,0.f,0.f};
    for (int s = s0; s < s1e; ++s) {
        float4 v = *(const float4*)(p + s * F_);
        a1.x += v.x; a1.y += v.y; a1.z += v.z; a1.w += v.w;
        a2.x += v.x*v.x; a2.y += v.y*v.y; a2.z += v.z*v.z; a2.w += v.w*v.w;
    }
    *(float4*)(s1p + part * BF + b * F_ + f) = a1;
    *(float4*)(s2p + part * BF + b * F_ + f) = a2;
}

// ---------------- K1b: combine the 8 partials (fully parallel, float4) ------------
__global__ void k_sum(const float* __restrict__ s1p, const float* __restrict__ s2p,
                      float* __restrict__ s1, float* __restrict__ s2) {
    int j = (blockIdx.x * 256 + threadIdx.x) * 4;    // 0..49148
    float4 a1 = {0.f,0.f,0.f,0.f}, a2 = {0.f,0.f,0.f,0.f};
#pragma unroll
    for (int p = 0; p < NSPLIT; ++p) {
        float4 v1 = *(const float4*)(s1p + p * BF + j);
        float4 v2 = *(const float4*)(s2p + p * BF + j);
        a1.x += v1.x; a1.y += v1.y; a1.z += v1.z; a1.w += v1.w;
        a2.x += v2.x; a2.y += v2.y; a2.z += v2.z; a2.w += v2.w;
    }
    *(float4*)(s1 + j) = a1;
    *(float4*)(s2 + j) = a2;
}

// ---------------- K2: per-domain stats (branchless selects, combined s1/s2) --------
__global__ void k_dom(const float* __restrict__ s1, const float* __restrict__ s2,
                      const int* __restrict__ domain,
                      const float* __restrict__ mean_buf, const float* __restrict__ var_buf,
                      float* __restrict__ nm_tab, float* __restrict__ sv_tab,
                      float* __restrict__ out_nm, float* __restrict__ out_nv) {
    int idx = blockIdx.x * 256 + threadIdx.x;    // 0..3071 = f*4+d
    if (idx >= F_ * 4) return;
    int f = idx >> 2, d = idx & 3;
    float a1 = 0.f, a2 = 0.f, cntf = 0.f;
#pragma unroll 8
    for (int b = 0; b < B_; ++b) {
        float v1 = s1[b * F_ + f];
        float v2 = s2[b * F_ + f];
        bool mk = (domain[b] == d);
        a1 += mk ? v1 : 0.0f;
        a2 += mk ? v2 : 0.0f;
        cntf += mk ? 1.0f : 0.0f;
    }
    float nm, nv;
    if (cntf > 0.f) {
        float n = cntf * (float)S_;
        float mu = a1 / n;
        float var = (a2 - n * mu * mu) / fmaxf(n - 1.0f, 1.0f);
        nm = 0.9f * mean_buf[d * F_ + f] + 0.1f * mu;
        nv = 0.9f * var_buf[d * F_ + f] + 0.1f * var;
    } else {
        nm = mean_buf[d * F_ + f];
        nv = var_buf[d * F_ + f];
    }
    out_nm[d * F_ + f] = nm;
    out_nv[d * F_ + f] = nv;
    nm_tab[d * F_ + f] = nm;
    sv_tab[d * F_ + f] = sqrtf(nv + 1e-6f);
}

// ---------------- K2b: per-(b,f) mix/hg coefficients (+ zero gram/loss) ------------
__global__ void k_coef(const float* __restrict__ s1, const float* __restrict__ s2,
                       const float* __restrict__ lmda,
                       const int* __restrict__ domain, const int* __restrict__ d_rand,
                       const float* __restrict__ nm_tab, const float* __restrict__ sv_tab,
                       float* __restrict__ c1, float* __restrict__ c0,
                       float* __restrict__ hgm, float* __restrict__ hgs,
                       float* __restrict__ gram, float* __restrict__ out_loss) {
    int t = blockIdx.x * 256 + threadIdx.x;      // 0..49151
    if (blockIdx.x < 144) gram[blockIdx.x * 256 + threadIdx.x] = 0.0f;
    if (blockIdx.x == 144 && threadIdx.x == 0) out_loss[0] = 0.0f;
    int b = t / F_, f = t - b * F_;
    float mu = s1[t] * (1.0f / (float)S_);
    float v  = (s2[t] - (float)S_ * mu * mu) * (1.0f / (float)(S_ - 1));
    float r  = rsqrtf(v + 1e-6f);
    int dm = domain[b];
    int ds = (dm + d_rand[b]) & 3;               // D == 4
    float sv = sv_tab[ds * F_ + f];
    float nm = nm_tab[ds * F_ + f];
    float lam = lmda[b];
    float rs = r * sv;
    c1[t] = lam + (1.0f - lam) * rs;
    c0[t] = (1.0f - lam) * (nm - mu * rs);
    hgm[t] = nm_tab[dm * F_ + f];
    hgs[t] = sv_tab[dm * F_ + f];
}

// ---------------- bf16 helpers ----------------
__device__ __forceinline__ uint pack2(float a, float b) {
    uint ua = __float_as_uint(a);
    uint ub = __float_as_uint(b);
    uint ha = (ua + 0x7FFFu + ((ua >> 16) & 1u)) >> 16;
    uint hb = (ub + 0x7FFFu + ((ub >> 16) & 1u)) & 0xFFFF0000u;
    return hb | ha;
}

// stage 8 floats (one granule) of one plane-row into swizzled LDS
__device__ __forceinline__ void bf16_store8(char* lds, int row, int g,
                                            float4 v0, float4 v1) {
    uint4 H;
    H.x = pack2(v0.x, v0.y);
    H.y = pack2(v0.z, v0.w);
    H.z = pack2(v1.x, v1.y);
    H.w = pack2(v1.z, v1.w);
    *(uint4*)(lds + row * 128 + ((g ^ (row & 7)) << 4)) = H;
}

__device__ __forceinline__ float4 fma4(float4 a, float4 x, float4 b) {
    float4 r;
    r.x = fmaf(a.x, x.x, b.x); r.y = fmaf(a.y, x.y, b.y);
    r.z = fmaf(a.z, x.z, b.z); r.w = fmaf(a.w, x.w, b.w);
    return r;
}

// ---------------- K3: fused x_mix/hg generation + MFMA Gram partials ----------------
// 256 blocks x 512 threads (8 waves, 1 block/CU, 2 waves/EU). Single bf16 plane.
// All six input streams register-prefetched across the barrier.
template <bool EXCL>
__global__ __launch_bounds__(512, 2)
void k_main(const float* __restrict__ x, const float* __restrict__ hgn,
            const float* __restrict__ c1, const float* __restrict__ c0,
            const float* __restrict__ hgm, const float* __restrict__ hgs,
            float* __restrict__ xmix, float* part, int npart) {
    __shared__ __align__(16) char LDS[24576];    // 192 rows x 128 B (bf16 x 64)
    float4v acc[6][3];
#pragma unroll
    for (int i = 0; i < 6; ++i)
#pragma unroll
        for (int j = 0; j < 3; ++j)
            acc[i][j] = (float4v){0.f, 0.f, 0.f, 0.f};

    int tid = threadIdx.x;
    int b = tid >> 3;             // staging row 0..63
    int g = tid & 7;              // granule (8 floats)
    int w = tid >> 6;             // wave 0..7
    int wr = (w >> 2) * 96, wc = (w & 3) * 48;
    int lane = tid & 63, m = lane & 15, qd = lane >> 4;

    int q = blockIdx.x;
    size_t goff; int cb;
    {
        int s = q / 12, f0 = (q - s * 12) * 64;
        goff = ((size_t)b * S_ + s) * F_ + f0 + (g << 3);
        cb = b * F_ + f0 + (g << 3);
    }
    float4 X0 = ((const float4*)(x + goff))[0];
    float4 X1 = ((const float4*)(x + goff))[1];
    float4 N0 = ((const float4*)(hgn + goff))[0];
    float4 N1 = ((const float4*)(hgn + goff))[1];
    float4 C1a = ((const float4*)(c1 + cb))[0], C1b = ((const float4*)(c1 + cb))[1];
    float4 C0a = ((const float4*)(c0 + cb))[0], C0b = ((const float4*)(c0 + cb))[1];
    float4 HMa = ((const float4*)(hgm + cb))[0], HMb = ((const float4*)(hgm + cb))[1];
    float4 HSa = ((const float4*)(hgs + cb))[0], HSb = ((const float4*)(hgs + cb))[1];

    for (; q < NCHUNK; q += GMAIN) {
        float4 M0 = fma4(C1a, X0, C0a);
        float4 M1 = fma4(C1b, X1, C0b);
        ((float4*)(xmix + goff))[0] = M0;
        ((float4*)(xmix + goff))[1] = M1;
        float4 H0 = fma4(HSa, N0, HMa);
        float4 H1 = fma4(HSb, N1, HMb);

        bf16_store8(LDS, b, g, X0, X1);
        bf16_store8(LDS, 64 + b, g, M0, M1);
        bf16_store8(LDS, 128 + b, g, H0, H1);
        __syncthreads();

        // prefetch next chunk (all six streams) while the MFMA section runs
        int qn = q + GMAIN;
        if (qn < NCHUNK) {
            int s = qn / 12, f0 = (qn - s * 12) * 64;
            goff = ((size_t)b * S_ + s) * F_ + f0 + (g << 3);
            cb = b * F_ + f0 + (g << 3);
            X0 = ((const float4*)(x + goff))[0];
            X1 = ((const float4*)(x + goff))[1];
            N0 = ((const float4*)(hgn + goff))[0];
            N1 = ((const float4*)(hgn + goff))[1];
            C1a = ((const float4*)(c1 + cb))[0]; C1b = ((const float4*)(c1 + cb))[1];
            C0a = ((const float4*)(c0 + cb))[0]; C0b = ((const float4*)(c0 + cb))[1];
            HMa = ((const float4*)(hgm + cb))[0]; HMb = ((const float4*)(hgm + cb))[1];
            HSa = ((const float4*)(hgs + cb))[0]; HSb = ((const float4*)(hgs + cb))[1];
        }

#pragma unroll
        for (int t = 0; t < 2; ++t) {
            short8v A[6];
#pragma unroll
            for (int i = 0; i < 6; ++i) {
                int row = wr + i * 16 + m;
                int go = (((t << 2) + qd) ^ (row & 7)) << 4;
                A[i] = *(const short8v*)(LDS + row * 128 + go);
            }
#pragma unroll
            for (int j = 0; j < 3; ++j) {
                int row = wc + j * 16 + m;
                int go = (((t << 2) + qd) ^ (row & 7)) << 4;
                short8v Bv = *(const short8v*)(LDS + row * 128 + go);
#pragma unroll
                for (int i = 0; i < 6; ++i)
                    acc[i][j] = __builtin_amdgcn_mfma_f32_16x16x32_bf16(A[i], Bv, acc[i][j], 0, 0, 0);
            }
        }
        __syncthreads();
    }

    float* dst = part + (size_t)(blockIdx.x % npart) * GSZ;
#pragma unroll
    for (int i = 0; i < 6; ++i)
#pragma unroll
        for (int j = 0; j < 3; ++j) {
            int base = (wr + i * 16 + qd * 4) * N3 + wc + j * 16 + m;
#pragma unroll
            for (int r = 0; r < 4; ++r) {
                int o = base + r * N3;
                if (EXCL) dst[o] = acc[i][j][r];
                else atomicAdd(dst + o, acc[i][j][r]);
            }
        }
}

// ---------------- K3b: reduce partial Grams (float4, atomic into zeroed gram) ------
__global__ void k_red(const float* __restrict__ part, float* __restrict__ gram, int npart) {
    int g  = blockIdx.x / 36;
    int jb = blockIdx.x % 36;
    int j = (jb * 256 + threadIdx.x) * 4;        // 0..36860 step 4
    int p0 = g * 32;
    int p1 = (p0 + 32 < npart) ? p0 + 32 : npart;
    float4 s = {0.f, 0.f, 0.f, 0.f};
    for (int p = p0; p < p1; ++p) {
        float4 v = *(const float4*)(part + (size_t)p * GSZ + j);
        s.x += v.x; s.y += v.y; s.z += v.z; s.w += v.w;
    }
    atomicAdd(gram + j,     s.x);
    atomicAdd(gram + j + 1, s.y);
    atomicAdd(gram + j + 2, s.z);
    atomicAdd(gram + j + 3, s.w);
}

// ---------------- K4: triplet hard loss (one block per row) ----------------
__global__ void k_loss(const float* __restrict__ gram, const int* __restrict__ labels,
                       float* __restrict__ out_loss) {
    __shared__ float sq[N3];
    __shared__ int ln[N3];
    int i = blockIdx.x, lane = threadIdx.x;      // 64 lanes
    for (int k = lane; k < N3; k += 64) {
        sq[k] = gram[k * (N3 + 1)];
        ln[k] = (k < 128) ? labels[k & 63] : -1;
    }
    __syncthreads();
    int li = ln[i];
    float si = sq[i];
    float ap = -1e30f, an = 1e30f;
    for (int j = lane; j < N3; j += 64) {
        float d2 = si + sq[j] - 2.0f * gram[i * N3 + j];
        float dist = sqrtf(fmaxf(d2, 1e-12f));
        bool pos = (li == ln[j]);
        ap = pos ? fmaxf(ap, dist) : ap;
        an = pos ? an : fminf(an, dist);
    }
#pragma unroll
    for (int off = 32; off; off >>= 1) {
        ap = fmaxf(ap, __shfl_xor(ap, off));
        an = fminf(an, __shfl_xor(an, off));
    }
    if (lane == 0) {
        float xv = ap - an;
        float sp = fmaxf(xv, 0.0f) + log1pf(expf(-fabsf(xv)));
        atomicAdd(out_loss, sp * (1.0f / (float)N3));
    }
}

extern "C" void kernel_launch(void* const* d_in, const int* in_sizes, int n_in,
                              void* d_out, int out_size, void* d_ws, size_t ws_size,
                              hipStream_t stream) {
    const float* x        = (const float*)d_in[0];
    const float* lmda     = (const float*)d_in[1];
    const float* mean_buf = (const float*)d_in[2];
    const float* var_buf  = (const float*)d_in[3];
    const float* hgn      = (const float*)d_in[4];
    const int*   labels   = (const int*)d_in[5];
    const int*   domain   = (const int*)d_in[6];
    const int*   d_rand   = (const int*)d_in[7];
    float* out = (float*)d_out;
    float* ws  = (float*)d_ws;

    long avail = (long)(ws_size / 4) - WS_PART;
    int npart = (int)(avail / GSZ);
    if (npart < 1) npart = 1;
    if (npart > GMAIN) npart = GMAIN;
    bool excl = (npart == GMAIN);
    int ngroups = (npart + 31) / 32;

    k_bf_stats<<<dim3(48 * NSPLIT), dim3(256), 0, stream>>>(x, ws + WS_S1P, ws + WS_S2P);
    k_sum<<<dim3(48), dim3(256), 0, stream>>>(ws + WS_S1P, ws + WS_S2P,
                                              ws + WS_S1, ws + WS_S2);
    k_dom<<<dim3(12), dim3(256), 0, stream>>>(ws + WS_S1, ws + WS_S2, domain,
                                              mean_buf, var_buf,
                                              ws + WS_NM, ws + WS_SV,
                                              out + OUT_NM, out + OUT_NV);
    k_coef<<<dim3(192), dim3(256), 0, stream>>>(ws + WS_S1, ws + WS_S2, lmda,
                                                domain, d_rand,
                                                ws + WS_NM, ws + WS_SV,
                                                ws + WS_C1, ws + WS_C0,
                                                ws + WS_HGM, ws + WS_HGS,
                                                ws + WS_GRAM, out + OUT_LOSS);
    if (!excl) {
        hipMemsetAsync(ws + WS_PART, 0, (size_t)npart * GSZ * 4, stream);
    }
    if (excl) {
        k_main<true><<<dim3(GMAIN), dim3(512), 0, stream>>>(
            x, hgn, ws + WS_C1, ws + WS_C0, ws + WS_HGM, ws + WS_HGS,
            out, ws + WS_PART, npart);
    } else {
        k_main<false><<<dim3(GMAIN), dim3(512), 0, stream>>>(
            x, hgn, ws + WS_C1, ws + WS_C0, ws + WS_HGM, ws + WS_HGS,
            out, ws + WS_PART, npart);
    }
    k_red<<<dim3(ngroups * 36), dim3(256), 0, stream>>>(ws + WS_PART, ws + WS_GRAM, npart);
    k_loss<<<dim3(N3), dim3(64), 0, stream>>>(ws + WS_GRAM, labels, out + OUT_LOSS);
}